// Round 1
// 1589.749 us; speedup vs baseline: 1.6037x; 1.6037x over previous
//
#include <hip/hip_runtime.h>

#define N_TOTAL 1024000
#define N_EDGES 16384000
#define SLOPE 0.01f
#define NBUCK 4000     // fine buckets of 256 dst nodes each (4000*256 == N_TOTAL)
#define BCAP  5120     // mean 4096 edges/bucket, +16 sigma slack
#define NCOARSE 250    // coarse buckets of 4096 dst nodes (16 fine buckets each)
#define CCAP 73472     // mean 65536 edges/coarse bucket, +31 sigma slack
#define CTILE 4096     // edges per partition tile (N_EDGES is an exact multiple)

__device__ __forceinline__ float lrelu(float v){ return v > 0.0f ? v : SLOPE*v; }

// ---------------- node kernels ----------------

// P[i] = x[i] @ w0a   (bias added later by aggregator)
__global__ void __launch_bounds__(256) k_init(const float* __restrict__ x,
                       const float* __restrict__ w,   // 16x8
                       float* __restrict__ P){
  int i = blockIdx.x*256 + threadIdx.x;
  if (i >= N_TOTAL) return;
  const float4* xr = (const float4*)(x + (size_t)i*16);
  float4 a0 = xr[0], a1 = xr[1], a2 = xr[2], a3 = xr[3];
  float xi[16] = {a0.x,a0.y,a0.z,a0.w, a1.x,a1.y,a1.z,a1.w,
                  a2.x,a2.y,a2.z,a2.w, a3.x,a3.y,a3.z,a3.w};
  float p[8];
  #pragma unroll
  for (int j=0;j<8;j++){
    float s = 0.f;
    #pragma unroll
    for (int k=0;k<16;k++) s += xi[k]*w[k*8+j];
    p[j] = s;
  }
  float4* Pr = (float4*)(P + (size_t)i*8);
  Pr[0] = make_float4(p[0],p[1],p[2],p[3]);
  Pr[1] = make_float4(p[4],p[5],p[6],p[7]);
}

// Q -> lrelu -> @wb+bb -> lrelu -> @wa -> P
__global__ void __launch_bounds__(256) k_mid(float* __restrict__ P, const float* __restrict__ Q,
                      const float* __restrict__ wb, const float* __restrict__ bb,
                      const float* __restrict__ wa){
  int i = blockIdx.x*256 + threadIdx.x;
  if (i >= N_TOTAL) return;
  const float4* Qr = (const float4*)(Q + (size_t)i*8);
  float4 q0 = Qr[0], q1 = Qr[1];
  float g[8] = {lrelu(q0.x),lrelu(q0.y),lrelu(q0.z),lrelu(q0.w),
                lrelu(q1.x),lrelu(q1.y),lrelu(q1.z),lrelu(q1.w)};
  float h[8];
  #pragma unroll
  for (int j=0;j<8;j++){
    float s = bb[j];
    #pragma unroll
    for (int k=0;k<8;k++) s += g[k]*wb[k*8+j];
    h[j] = lrelu(s);
  }
  float p[8];
  #pragma unroll
  for (int j=0;j<8;j++){
    float s = 0.f;
    #pragma unroll
    for (int k=0;k<8;k++) s += h[k]*wa[k*8+j];
    p[j] = s;
  }
  float4* Pr = (float4*)(P + (size_t)i*8);
  Pr[0] = make_float4(p[0],p[1],p[2],p[3]);
  Pr[1] = make_float4(p[4],p[5],p[6],p[7]);
}

// ---------------- two-level LDS-staged radix partition ----------------
// Pass 1: edges -> 250 coarse buckets (dst>>12). Payload = (dst&4095)<<20 | src.
// Per 4096-edge tile: LDS hist+rank, scan, one reservation atomic per bucket,
// LDS reorder, then bucket-contiguous coalesced write-out (~64B runs).
__global__ void __launch_bounds__(256) k_part1(const int* __restrict__ src, const int* __restrict__ dst,
                                               int* __restrict__ cntC, int* __restrict__ coarse){
  __shared__ int ebuf[CTILE];
  __shared__ unsigned char bkt[CTILE];
  __shared__ int hist[256], tmp[256], exS[256], delta[256];
  int tid = threadIdx.x;
  int tileBase = blockIdx.x * CTILE;
  hist[tid] = 0;
  __syncthreads();
  int pay[16]; int rnk[16]; int bk[16];
  #pragma unroll
  for (int k=0;k<16;k++){
    int idx = tileBase + k*256 + tid;
    int d = dst[idx], s = src[idx];
    int b = d >> 12;
    pay[k] = ((d & 4095) << 20) | s;
    bk[k] = b;
    rnk[k] = atomicAdd(&hist[b], 1);
  }
  __syncthreads();
  int v = hist[tid];
  tmp[tid] = v; __syncthreads();
  for (int off=1; off<256; off<<=1){
    int t2 = (tid>=off) ? tmp[tid-off] : 0; __syncthreads();
    tmp[tid] += t2; __syncthreads();
  }
  int ex = tmp[tid] - v;
  exS[tid] = ex;
  if (tid < NCOARSE && v > 0){
    int g = atomicAdd(&cntC[tid], v);
    delta[tid] = g - ex;
  }
  __syncthreads();
  #pragma unroll
  for (int k=0;k<16;k++){
    int p = exS[bk[k]] + rnk[k];
    ebuf[p] = pay[k];
    bkt[p] = (unsigned char)bk[k];
  }
  __syncthreads();
  for (int i = tid; i < CTILE; i += 256){
    int b = bkt[i];
    int lp = delta[b] + i;               // global position within bucket
    if ((unsigned)lp < CCAP) coarse[b*CCAP + lp] = ebuf[i];
  }
}

// Pass 2: each coarse bucket -> its 16 fine buckets (256 nodes each).
// Same rank-reorder scheme, 16-way; write runs of ~256 entries (1KB).
// Output payload (local<<20)|src matches what k_csr expects.
__global__ void __launch_bounds__(256) k_part2(const int* __restrict__ coarse, const int* __restrict__ cntC,
                                               int* __restrict__ cntF, int* __restrict__ packed){
  __shared__ int ebuf[CTILE];
  __shared__ unsigned char bkt[CTILE];
  __shared__ int hist[16], tmp16[16], exS[16], delta[16];
  int tid = threadIdx.x;
  int c = blockIdx.x;
  int n = cntC[c]; if (n > CCAP) n = CCAP;
  int tileBase = blockIdx.y * CTILE;
  if (tileBase >= n) return;            // uniform across block, safe
  int cntE = n - tileBase; if (cntE > CTILE) cntE = CTILE;
  if (tid < 16) hist[tid] = 0;
  __syncthreads();
  unsigned pay[16]; int rnk[16]; int bk[16];
  const int* reg = coarse + (size_t)c*CCAP + tileBase;
  #pragma unroll
  for (int k=0;k<16;k++){
    int idx = k*256 + tid;
    bk[k] = -1;
    if (idx < cntE){
      unsigned e = (unsigned)reg[idx];
      int f = (int)(e >> 28);           // top 4 bits of 12-bit local dst
      pay[k] = e & 0x0FFFFFFFu;         // (dst&255)<<20 | src
      bk[k] = f;
      rnk[k] = atomicAdd(&hist[f], 1);
    }
  }
  __syncthreads();
  if (tid < 16) tmp16[tid] = hist[tid];
  __syncthreads();
  for (int off=1; off<16; off<<=1){
    int t2 = 0;
    if (tid < 16 && tid >= off) t2 = tmp16[tid-off];
    __syncthreads();
    if (tid < 16) tmp16[tid] += t2;
    __syncthreads();
  }
  if (tid < 16){
    int vv = hist[tid];
    int ex = tmp16[tid] - vv;
    exS[tid] = ex;
    if (vv > 0) delta[tid] = atomicAdd(&cntF[c*16 + tid], vv) - ex;
  }
  __syncthreads();
  #pragma unroll
  for (int k=0;k<16;k++){
    if (bk[k] >= 0){
      int p = exS[bk[k]] + rnk[k];
      ebuf[p] = (int)pay[k];
      bkt[p] = (unsigned char)bk[k];
    }
  }
  __syncthreads();
  for (int i = tid; i < cntE; i += 256){
    int f = bkt[i];
    int lp = delta[f] + i;
    if ((unsigned)lp < BCAP) packed[(size_t)(c*16 + f)*BCAP + lp] = ebuf[i];
  }
}

// ---------------- legacy single-pass binning (kept as fallback) ----------------
__global__ void __launch_bounds__(256) k_bin(const int* __restrict__ src, const int* __restrict__ dst,
                                             int* __restrict__ cnt, int* __restrict__ packed){
  int t = blockIdx.x*256 + threadIdx.x;
  if (t >= N_EDGES) return;
  int d = dst[t], s = src[t];
  int b = d >> 8, l = d & 255;
  int p = atomicAdd(&cnt[b], 1);
  if (p < BCAP) packed[b*BCAP + p] = (l << 20) | s;
}

// Per bucket: LDS-stage edges, hist+scan over 256 local nodes,
// rewrite bucket region in place as per-node-sorted src lists; emit (beg,end).
__global__ void __launch_bounds__(256) k_csr(int* __restrict__ packed, const int* __restrict__ cnt,
                                             int2* __restrict__ row2){
  __shared__ int ebuf[BCAP];
  __shared__ int hist[256], pos[256], tmp[256];
  int b = blockIdx.x, tid = threadIdx.x;
  int n = cnt[b]; if (n > BCAP) n = BCAP;
  int* region = packed + (size_t)b*BCAP;
  hist[tid] = 0;
  __syncthreads();
  for (int i = tid; i < n; i += 256){
    int e = region[i];
    ebuf[i] = e;
    atomicAdd(&hist[e >> 20], 1);
  }
  __syncthreads();
  int v = hist[tid];
  tmp[tid] = v; __syncthreads();
  for (int off=1; off<256; off<<=1){
    int t2 = (tid>=off) ? tmp[tid-off] : 0; __syncthreads();
    tmp[tid] += t2; __syncthreads();
  }
  int ex = tmp[tid] - v;                 // exclusive scan
  pos[tid] = ex;
  int base = b*BCAP;
  row2[b*256 + tid] = make_int2(base + ex, base + ex + v);
  __syncthreads();
  for (int i = tid; i < n; i += 256){
    int e = ebuf[i];
    int l = e >> 20, s = e & 0xFFFFF;
    int p = atomicAdd(&pos[l], 1);
    region[p] = s;
  }
}

// ---------------- aggregation (no atomics) ----------------
// Q[i][j] = P[i][j] + b[j] + sum_{s in N(i)} P[s][j]; 8 lanes per node
__global__ void __launch_bounds__(256) k_agg(const float* __restrict__ P,
                                             const int2* __restrict__ row2,
                                             const int* __restrict__ csr,
                                             const float* __restrict__ b,
                                             float* __restrict__ Q){
  int t = blockIdx.x*256 + threadIdx.x;
  int node = t >> 3;
  int j = t & 7;
  if (node >= N_TOTAL) return;
  int2 r = row2[node];
  float acc = P[(size_t)node*8 + j] + b[j];
  int e = r.x;
  for (; e+3 < r.y; e += 4){
    int s0 = csr[e], s1 = csr[e+1], s2 = csr[e+2], s3 = csr[e+3];
    float v0 = P[(size_t)s0*8 + j];
    float v1 = P[(size_t)s1*8 + j];
    float v2 = P[(size_t)s2*8 + j];
    float v3 = P[(size_t)s3*8 + j];
    acc += v0; acc += v1; acc += v2; acc += v3;
  }
  for (; e < r.y; e++) acc += P[(size_t)csr[e]*8 + j];
  Q[(size_t)node*8 + j] = acc;
}

// ---------------- fallback (atomic path) ----------------
__global__ void __launch_bounds__(256) k_qinit(const float* __restrict__ P, const float* __restrict__ b,
                                               float* __restrict__ Q){
  int t = blockIdx.x*256 + threadIdx.x;
  if (t < N_TOTAL*8) Q[t] = P[t] + b[t & 7];
}

__global__ void __launch_bounds__(256) k_scatter(const int* __restrict__ src,
                                                 const int* __restrict__ dst,
                                                 const float* __restrict__ P,
                                                 float* __restrict__ Q){
  int t = blockIdx.x*256 + threadIdx.x;
  int e = t >> 3;
  int j = t & 7;
  int s = src[e];
  int d = dst[e];
  float v = P[(size_t)s*8 + j];
  atomicAdd(Q + (size_t)d*8 + j, v);
}

// ---------------- readout ----------------
__global__ void __launch_bounds__(256) k_readout(const float* __restrict__ Q,
                          const float* __restrict__ wb, const float* __restrict__ bb,
                          const float* __restrict__ fc1w, const float* __restrict__ fc1b,
                          const float* __restrict__ fc2w, const float* __restrict__ fc2b,
                          float* __restrict__ out){
  int bi = blockIdx.x;
  int tid = threadIdx.x;
  float acc0 = 0.f, acc1 = 0.f;
  for (int n = tid; n < 2000; n += 256){
    size_t i = (size_t)bi*2000 + n;
    const float4* qr = (const float4*)(Q + i*8);
    float4 q0 = qr[0], q1 = qr[1];
    float g[8] = {lrelu(q0.x),lrelu(q0.y),lrelu(q0.z),lrelu(q0.w),
                  lrelu(q1.x),lrelu(q1.y),lrelu(q1.z),lrelu(q1.w)};
    float s = fc1b[0];
    #pragma unroll
    for (int j=0;j<8;j++){
      float h = bb[j];
      #pragma unroll
      for (int k=0;k<8;k++) h += g[k]*wb[k*8+j];
      s += lrelu(h)*fc1w[j];
    }
    float t = lrelu(s);
    acc0 += t*fc2w[n*2+0];
    acc1 += t*fc2w[n*2+1];
  }
  #pragma unroll
  for (int off = 32; off > 0; off >>= 1){
    acc0 += __shfl_down(acc0, off);
    acc1 += __shfl_down(acc1, off);
  }
  __shared__ float s0[4], s1[4];
  int w = tid >> 6;
  if ((tid & 63) == 0){ s0[w] = acc0; s1[w] = acc1; }
  __syncthreads();
  if (tid == 0){
    float z0 = s0[0]+s0[1]+s0[2]+s0[3] + fc2b[0];
    float z1 = s1[0]+s1[1]+s1[2]+s1[3] + fc2b[1];
    float m = fmaxf(z0, z1);
    float lse = m + logf(expf(z0-m) + expf(z1-m));
    out[bi*2+0] = z0 - lse;
    out[bi*2+1] = z1 - lse;
  }
}

extern "C" void kernel_launch(void* const* d_in, const int* in_sizes, int n_in,
                              void* d_out, int out_size, void* d_ws, size_t ws_size,
                              hipStream_t stream){
  const float* x   = (const float*)d_in[0];
  const int*   ei  = (const int*)d_in[1];
  const int*   src = ei;
  const int*   dst = ei + N_EDGES;
  const float* w0a=(const float*)d_in[3],  *b0a=(const float*)d_in[4];
  const float* w0b=(const float*)d_in[5],  *b0b=(const float*)d_in[6];
  const float* w1a=(const float*)d_in[7],  *b1a=(const float*)d_in[8];
  const float* w1b=(const float*)d_in[9],  *b1b=(const float*)d_in[10];
  const float* w2a=(const float*)d_in[11], *b2a=(const float*)d_in[12];
  const float* w2b=(const float*)d_in[13], *b2b=(const float*)d_in[14];
  const float* w3a=(const float*)d_in[15], *b3a=(const float*)d_in[16];
  const float* w3b=(const float*)d_in[17], *b3b=(const float*)d_in[18];
  const float* fc1w=(const float*)d_in[19],*fc1b=(const float*)d_in[20];
  const float* fc2w=(const float*)d_in[21],*fc2b=(const float*)d_in[22];
  float* out = (float*)d_out;

  // workspace layout (unchanged size: 155.7 MB)
  char* base = (char*)d_ws;
  float* P      = (float*)base;  base += (size_t)N_TOTAL*8*4;        // 32.77 MB
  float* Q      = (float*)base;  base += (size_t)N_TOTAL*8*4;        // 32.77 MB
  size_t atomic_need = (size_t)(base - (char*)d_ws);
  int2*  row2   = (int2*)base;   base += (size_t)N_TOTAL*8;          // 8.19 MB
  int*   cnt    = (int*)base;    base += 4096*4;                     // 16 KB (fine counters)
  int*   packed = (int*)base;    base += (size_t)NBUCK*BCAP*4;       // 81.92 MB
  size_t need = (size_t)(base - (char*)d_ws);

  // coarse staging aliases [P|Q|row2] (73.7 MB); those are written only AFTER
  // partitioning completes (k_csr writes row2, then k_init writes P, k_agg writes Q)
  int* coarse = (int*)P;                               // NCOARSE*CCAP ints = 73.47 MB
  int* cntC   = coarse + (size_t)NCOARSE*CCAP;         // 250 ints, still inside alias area

  const int nb_nodes = (N_TOTAL + 255)/256;     // 4000
  const int nb_edges = (N_EDGES + 255)/256;     // 64000
  const int nb_nf    = (N_TOTAL*8 + 255)/256;   // 32000

  if (ws_size >= need){
    // ---- two-level LDS-staged partition + CSR build (reused by all 4 layers) ----
    hipMemsetAsync(cnt, 0, (size_t)NBUCK*4, stream);
    hipMemsetAsync(cntC, 0, (size_t)NCOARSE*4, stream);
    k_part1<<<N_EDGES/CTILE,256,0,stream>>>(src, dst, cntC, coarse);
    dim3 g2(NCOARSE, (CCAP + CTILE - 1)/CTILE);        // 250 x 18
    k_part2<<<g2,256,0,stream>>>(coarse, cntC, cnt, packed);
    k_csr<<<NBUCK,256,0,stream>>>(packed, cnt, row2);

    k_init<<<nb_nodes,256,0,stream>>>(x, w0a, P);
    k_agg <<<nb_nf,256,0,stream>>>(P, row2, packed, b0a, Q);
    k_mid <<<nb_nodes,256,0,stream>>>(P, Q, w0b, b0b, w1a);
    k_agg <<<nb_nf,256,0,stream>>>(P, row2, packed, b1a, Q);
    k_mid <<<nb_nodes,256,0,stream>>>(P, Q, w1b, b1b, w2a);
    k_agg <<<nb_nf,256,0,stream>>>(P, row2, packed, b2a, Q);
    k_mid <<<nb_nodes,256,0,stream>>>(P, Q, w2b, b2b, w3a);
    k_agg <<<nb_nf,256,0,stream>>>(P, row2, packed, b3a, Q);
  } else if (ws_size >= atomic_need){
    // ---- atomic fallback ----
    k_init<<<nb_nodes,256,0,stream>>>(x, w0a, P);
    k_qinit<<<nb_nf,256,0,stream>>>(P, b0a, Q);
    k_scatter<<<(N_EDGES*8)/256,256,0,stream>>>(src,dst,P,Q);
    k_mid <<<nb_nodes,256,0,stream>>>(P, Q, w0b, b0b, w1a);
    k_qinit<<<nb_nf,256,0,stream>>>(P, b1a, Q);
    k_scatter<<<(N_EDGES*8)/256,256,0,stream>>>(src,dst,P,Q);
    k_mid <<<nb_nodes,256,0,stream>>>(P, Q, w1b, b1b, w2a);
    k_qinit<<<nb_nf,256,0,stream>>>(P, b2a, Q);
    k_scatter<<<(N_EDGES*8)/256,256,0,stream>>>(src,dst,P,Q);
    k_mid <<<nb_nodes,256,0,stream>>>(P, Q, w2b, b2b, w3a);
    k_qinit<<<nb_nf,256,0,stream>>>(P, b3a, Q);
    k_scatter<<<(N_EDGES*8)/256,256,0,stream>>>(src,dst,P,Q);
  }
  k_readout<<<512,256,0,stream>>>(Q,w3b,b3b,fc1w,fc1b,fc2w,fc2b,out);
}

// Round 2
// 1556.359 us; speedup vs baseline: 1.6381x; 1.0215x over previous
//
#include <hip/hip_runtime.h>

#define N_TOTAL 1024000
#define N_EDGES 16384000
#define SLOPE 0.01f
#define NBUCK 4000     // fine buckets of 256 dst nodes each (4000*256 == N_TOTAL)
#define BCAP  5120     // mean 4096 edges/bucket, +16 sigma slack
#define NCOARSE 250    // coarse buckets of 4096 dst nodes (16 fine buckets each)
#define CCAP 73472     // mean 65536 edges/coarse bucket, +31 sigma slack
#define CTILE 4096     // edges per partition tile (N_EDGES is an exact multiple)

__device__ __forceinline__ float lrelu(float v){ return v > 0.0f ? v : SLOPE*v; }
__device__ __forceinline__ float4 f4add(float4 a, float4 b){
  return make_float4(a.x+b.x, a.y+b.y, a.z+b.z, a.w+b.w);
}
__device__ __forceinline__ float4 shfl_xor4(float4 v, int m){
  return make_float4(__shfl_xor(v.x,m), __shfl_xor(v.y,m),
                     __shfl_xor(v.z,m), __shfl_xor(v.w,m));
}

// ---------------- node kernels ----------------

// P[i] = x[i] @ w0a   (bias added later by aggregator)
__global__ void __launch_bounds__(256) k_init(const float* __restrict__ x,
                       const float* __restrict__ w,   // 16x8
                       float* __restrict__ P){
  int i = blockIdx.x*256 + threadIdx.x;
  if (i >= N_TOTAL) return;
  const float4* xr = (const float4*)(x + (size_t)i*16);
  float4 a0 = xr[0], a1 = xr[1], a2 = xr[2], a3 = xr[3];
  float xi[16] = {a0.x,a0.y,a0.z,a0.w, a1.x,a1.y,a1.z,a1.w,
                  a2.x,a2.y,a2.z,a2.w, a3.x,a3.y,a3.z,a3.w};
  float p[8];
  #pragma unroll
  for (int j=0;j<8;j++){
    float s = 0.f;
    #pragma unroll
    for (int k=0;k<16;k++) s += xi[k]*w[k*8+j];
    p[j] = s;
  }
  float4* Pr = (float4*)(P + (size_t)i*8);
  Pr[0] = make_float4(p[0],p[1],p[2],p[3]);
  Pr[1] = make_float4(p[4],p[5],p[6],p[7]);
}

// kept for the atomic fallback path
__global__ void __launch_bounds__(256) k_mid(float* __restrict__ P, const float* __restrict__ Q,
                      const float* __restrict__ wb, const float* __restrict__ bb,
                      const float* __restrict__ wa){
  int i = blockIdx.x*256 + threadIdx.x;
  if (i >= N_TOTAL) return;
  const float4* Qr = (const float4*)(Q + (size_t)i*8);
  float4 q0 = Qr[0], q1 = Qr[1];
  float g[8] = {lrelu(q0.x),lrelu(q0.y),lrelu(q0.z),lrelu(q0.w),
                lrelu(q1.x),lrelu(q1.y),lrelu(q1.z),lrelu(q1.w)};
  float h[8];
  #pragma unroll
  for (int j=0;j<8;j++){
    float s = bb[j];
    #pragma unroll
    for (int k=0;k<8;k++) s += g[k]*wb[k*8+j];
    h[j] = lrelu(s);
  }
  float p[8];
  #pragma unroll
  for (int j=0;j<8;j++){
    float s = 0.f;
    #pragma unroll
    for (int k=0;k<8;k++) s += h[k]*wa[k*8+j];
    p[j] = s;
  }
  float4* Pr = (float4*)(P + (size_t)i*8);
  Pr[0] = make_float4(p[0],p[1],p[2],p[3]);
  Pr[1] = make_float4(p[4],p[5],p[6],p[7]);
}

// ---------------- two-level LDS-staged radix partition ----------------
__global__ void __launch_bounds__(256) k_part1(const int* __restrict__ src, const int* __restrict__ dst,
                                               int* __restrict__ cntC, int* __restrict__ coarse){
  __shared__ int ebuf[CTILE];
  __shared__ unsigned char bkt[CTILE];
  __shared__ int hist[256], tmp[256], exS[256], delta[256];
  int tid = threadIdx.x;
  int tileBase = blockIdx.x * CTILE;
  hist[tid] = 0;
  __syncthreads();
  int pay[16]; int rnk[16]; int bk[16];
  #pragma unroll
  for (int k=0;k<16;k++){
    int idx = tileBase + k*256 + tid;
    int d = dst[idx], s = src[idx];
    int b = d >> 12;
    pay[k] = ((d & 4095) << 20) | s;
    bk[k] = b;
    rnk[k] = atomicAdd(&hist[b], 1);
  }
  __syncthreads();
  int v = hist[tid];
  tmp[tid] = v; __syncthreads();
  for (int off=1; off<256; off<<=1){
    int t2 = (tid>=off) ? tmp[tid-off] : 0; __syncthreads();
    tmp[tid] += t2; __syncthreads();
  }
  int ex = tmp[tid] - v;
  exS[tid] = ex;
  if (tid < NCOARSE && v > 0){
    int g = atomicAdd(&cntC[tid], v);
    delta[tid] = g - ex;
  }
  __syncthreads();
  #pragma unroll
  for (int k=0;k<16;k++){
    int p = exS[bk[k]] + rnk[k];
    ebuf[p] = pay[k];
    bkt[p] = (unsigned char)bk[k];
  }
  __syncthreads();
  for (int i = tid; i < CTILE; i += 256){
    int b = bkt[i];
    int lp = delta[b] + i;               // global position within bucket
    if ((unsigned)lp < CCAP) coarse[b*CCAP + lp] = ebuf[i];
  }
}

__global__ void __launch_bounds__(256) k_part2(const int* __restrict__ coarse, const int* __restrict__ cntC,
                                               int* __restrict__ cntF, int* __restrict__ packed){
  __shared__ int ebuf[CTILE];
  __shared__ unsigned char bkt[CTILE];
  __shared__ int hist[16], tmp16[16], exS[16], delta[16];
  int tid = threadIdx.x;
  int c = blockIdx.x;
  int n = cntC[c]; if (n > CCAP) n = CCAP;
  int tileBase = blockIdx.y * CTILE;
  if (tileBase >= n) return;            // uniform across block, safe
  int cntE = n - tileBase; if (cntE > CTILE) cntE = CTILE;
  if (tid < 16) hist[tid] = 0;
  __syncthreads();
  unsigned pay[16]; int rnk[16]; int bk[16];
  const int* reg = coarse + (size_t)c*CCAP + tileBase;
  #pragma unroll
  for (int k=0;k<16;k++){
    int idx = k*256 + tid;
    bk[k] = -1;
    if (idx < cntE){
      unsigned e = (unsigned)reg[idx];
      int f = (int)(e >> 28);           // top 4 bits of 12-bit local dst
      pay[k] = e & 0x0FFFFFFFu;         // (dst&255)<<20 | src
      bk[k] = f;
      rnk[k] = atomicAdd(&hist[f], 1);
    }
  }
  __syncthreads();
  if (tid < 16) tmp16[tid] = hist[tid];
  __syncthreads();
  for (int off=1; off<16; off<<=1){
    int t2 = 0;
    if (tid < 16 && tid >= off) t2 = tmp16[tid-off];
    __syncthreads();
    if (tid < 16) tmp16[tid] += t2;
    __syncthreads();
  }
  if (tid < 16){
    int vv = hist[tid];
    int ex = tmp16[tid] - vv;
    exS[tid] = ex;
    if (vv > 0) delta[tid] = atomicAdd(&cntF[c*16 + tid], vv) - ex;
  }
  __syncthreads();
  #pragma unroll
  for (int k=0;k<16;k++){
    if (bk[k] >= 0){
      int p = exS[bk[k]] + rnk[k];
      ebuf[p] = (int)pay[k];
      bkt[p] = (unsigned char)bk[k];
    }
  }
  __syncthreads();
  for (int i = tid; i < cntE; i += 256){
    int f = bkt[i];
    int lp = delta[f] + i;
    if ((unsigned)lp < BCAP) packed[(size_t)(c*16 + f)*BCAP + lp] = ebuf[i];
  }
}

// Per bucket: LDS-stage edges, hist+scan over 256 local nodes,
// rewrite bucket region in place as per-node-sorted src lists; emit (beg,end).
__global__ void __launch_bounds__(256) k_csr(int* __restrict__ packed, const int* __restrict__ cnt,
                                             int2* __restrict__ row2){
  __shared__ int ebuf[BCAP];
  __shared__ int hist[256], pos[256], tmp[256];
  int b = blockIdx.x, tid = threadIdx.x;
  int n = cnt[b]; if (n > BCAP) n = BCAP;
  int* region = packed + (size_t)b*BCAP;
  hist[tid] = 0;
  __syncthreads();
  for (int i = tid; i < n; i += 256){
    int e = region[i];
    ebuf[i] = e;
    atomicAdd(&hist[e >> 20], 1);
  }
  __syncthreads();
  int v = hist[tid];
  tmp[tid] = v; __syncthreads();
  for (int off=1; off<256; off<<=1){
    int t2 = (tid>=off) ? tmp[tid-off] : 0; __syncthreads();
    tmp[tid] += t2; __syncthreads();
  }
  int ex = tmp[tid] - v;                 // exclusive scan
  pos[tid] = ex;
  int base = b*BCAP;
  row2[b*256 + tid] = make_int2(base + ex, base + ex + v);
  __syncthreads();
  for (int i = tid; i < n; i += 256){
    int e = ebuf[i];
    int l = e >> 20, s = e & 0xFFFFF;
    int p = atomicAdd(&pos[l], 1);
    region[p] = s;
  }
}

// ---------------- aggregation (vectorized gather, fused MLP) ----------------
// One octet (8 lanes) per node. Lane l handles (edge-offset l>>1, half-row l&1):
// float4 gathers cover 4 edges per wave-instruction; 8 edges in flight per iter.
// Parity shfl_xor reduce leaves half0 in lane0, half1 in lane1.
// FUSE=1: apply lrelu -> @wb+bb -> lrelu -> @wa in-register, write next P.
// FUSE=0: write Q = agg @ wa + ba (readout consumes it).
template<int FUSE>
__global__ void __launch_bounds__(256) k_aggf(const float* __restrict__ Pin,
                                              const int2* __restrict__ row2,
                                              const int* __restrict__ csr,
                                              const float* __restrict__ bias,   // this layer's ba
                                              const float* __restrict__ wb,     // MLP lin2 (8x8)
                                              const float* __restrict__ bb,     // MLP lin2 bias
                                              const float* __restrict__ wa,     // next layer lin1 (8x8)
                                              float* __restrict__ Out){
  int t = blockIdx.x*256 + threadIdx.x;
  int node = t >> 3, l = t & 7;
  int half = l & 1, eo = l >> 1;
  int2 r = row2[node];
  float4 acc;
  if (l < 2){
    float4 own = *(const float4*)(Pin + (size_t)node*8 + half*4);
    acc = make_float4(own.x + bias[half*4+0], own.y + bias[half*4+1],
                      own.z + bias[half*4+2], own.w + bias[half*4+3]);
  } else {
    acc = make_float4(0.f,0.f,0.f,0.f);
  }
  for (int e = r.x; e < r.y; e += 8){
    int i0 = e + eo, i1 = e + 4 + eo;
    if (i0 < r.y){
      int s0 = csr[i0];
      acc = f4add(acc, *(const float4*)(Pin + (size_t)s0*8 + half*4));
    }
    if (i1 < r.y){
      int s1 = csr[i1];
      acc = f4add(acc, *(const float4*)(Pin + (size_t)s1*8 + half*4));
    }
  }
  acc = f4add(acc, shfl_xor4(acc, 2));
  acc = f4add(acc, shfl_xor4(acc, 4));
  if (l >= 2) return;
  // lanes 0,1 hold Q-row halves
  if (!FUSE){
    *(float4*)(Out + (size_t)node*8 + half*4) = acc;
    return;
  }
  // exchange halves -> full g[8] per lane
  float g0 = lrelu(acc.x), g1 = lrelu(acc.y), g2 = lrelu(acc.z), g3 = lrelu(acc.w);
  float o0 = __shfl_xor(g0,1), o1 = __shfl_xor(g1,1), o2 = __shfl_xor(g2,1), o3 = __shfl_xor(g3,1);
  float gl[8];
  gl[half*4+0]=g0; gl[half*4+1]=g1; gl[half*4+2]=g2; gl[half*4+3]=g3;
  gl[(1-half)*4+0]=o0; gl[(1-half)*4+1]=o1; gl[(1-half)*4+2]=o2; gl[(1-half)*4+3]=o3;
  // h = lrelu(gl @ wb + bb), each lane computes its half of h
  float h[4];
  #pragma unroll
  for (int jj=0;jj<4;jj++){
    int j = half*4 + jj;
    float s = bb[j];
    #pragma unroll
    for (int k=0;k<8;k++) s += gl[k]*wb[k*8+j];
    h[jj] = lrelu(s);
  }
  // exchange h halves -> full h[8]
  float ho0 = __shfl_xor(h[0],1), ho1 = __shfl_xor(h[1],1), ho2 = __shfl_xor(h[2],1), ho3 = __shfl_xor(h[3],1);
  float hl[8];
  hl[half*4+0]=h[0]; hl[half*4+1]=h[1]; hl[half*4+2]=h[2]; hl[half*4+3]=h[3];
  hl[(1-half)*4+0]=ho0; hl[(1-half)*4+1]=ho1; hl[(1-half)*4+2]=ho2; hl[(1-half)*4+3]=ho3;
  // p = hl @ wa, write this lane's half of next P
  float4 p;
  {
    int j = half*4;
    float s0=0.f,s1=0.f,s2=0.f,s3=0.f;
    #pragma unroll
    for (int k=0;k<8;k++){
      float hv = hl[k];
      s0 += hv*wa[k*8+j+0];
      s1 += hv*wa[k*8+j+1];
      s2 += hv*wa[k*8+j+2];
      s3 += hv*wa[k*8+j+3];
    }
    p = make_float4(s0,s1,s2,s3);
  }
  *(float4*)(Out + (size_t)node*8 + half*4) = p;
}

// ---------------- fallback (atomic path) ----------------
__global__ void __launch_bounds__(256) k_qinit(const float* __restrict__ P, const float* __restrict__ b,
                                               float* __restrict__ Q){
  int t = blockIdx.x*256 + threadIdx.x;
  if (t < N_TOTAL*8) Q[t] = P[t] + b[t & 7];
}

__global__ void __launch_bounds__(256) k_scatter(const int* __restrict__ src,
                                                 const int* __restrict__ dst,
                                                 const float* __restrict__ P,
                                                 float* __restrict__ Q){
  int t = blockIdx.x*256 + threadIdx.x;
  int e = t >> 3;
  int j = t & 7;
  int s = src[e];
  int d = dst[e];
  float v = P[(size_t)s*8 + j];
  atomicAdd(Q + (size_t)d*8 + j, v);
}

// ---------------- readout ----------------
__global__ void __launch_bounds__(256) k_readout(const float* __restrict__ Q,
                          const float* __restrict__ wb, const float* __restrict__ bb,
                          const float* __restrict__ fc1w, const float* __restrict__ fc1b,
                          const float* __restrict__ fc2w, const float* __restrict__ fc2b,
                          float* __restrict__ out){
  int bi = blockIdx.x;
  int tid = threadIdx.x;
  float acc0 = 0.f, acc1 = 0.f;
  for (int n = tid; n < 2000; n += 256){
    size_t i = (size_t)bi*2000 + n;
    const float4* qr = (const float4*)(Q + i*8);
    float4 q0 = qr[0], q1 = qr[1];
    float g[8] = {lrelu(q0.x),lrelu(q0.y),lrelu(q0.z),lrelu(q0.w),
                  lrelu(q1.x),lrelu(q1.y),lrelu(q1.z),lrelu(q1.w)};
    float s = fc1b[0];
    #pragma unroll
    for (int j=0;j<8;j++){
      float h = bb[j];
      #pragma unroll
      for (int k=0;k<8;k++) h += g[k]*wb[k*8+j];
      s += lrelu(h)*fc1w[j];
    }
    float t = lrelu(s);
    acc0 += t*fc2w[n*2+0];
    acc1 += t*fc2w[n*2+1];
  }
  #pragma unroll
  for (int off = 32; off > 0; off >>= 1){
    acc0 += __shfl_down(acc0, off);
    acc1 += __shfl_down(acc1, off);
  }
  __shared__ float s0[4], s1[4];
  int w = tid >> 6;
  if ((tid & 63) == 0){ s0[w] = acc0; s1[w] = acc1; }
  __syncthreads();
  if (tid == 0){
    float z0 = s0[0]+s0[1]+s0[2]+s0[3] + fc2b[0];
    float z1 = s1[0]+s1[1]+s1[2]+s1[3] + fc2b[1];
    float m = fmaxf(z0, z1);
    float lse = m + logf(expf(z0-m) + expf(z1-m));
    out[bi*2+0] = z0 - lse;
    out[bi*2+1] = z1 - lse;
  }
}

extern "C" void kernel_launch(void* const* d_in, const int* in_sizes, int n_in,
                              void* d_out, int out_size, void* d_ws, size_t ws_size,
                              hipStream_t stream){
  const float* x   = (const float*)d_in[0];
  const int*   ei  = (const int*)d_in[1];
  const int*   src = ei;
  const int*   dst = ei + N_EDGES;
  const float* w0a=(const float*)d_in[3],  *b0a=(const float*)d_in[4];
  const float* w0b=(const float*)d_in[5],  *b0b=(const float*)d_in[6];
  const float* w1a=(const float*)d_in[7],  *b1a=(const float*)d_in[8];
  const float* w1b=(const float*)d_in[9],  *b1b=(const float*)d_in[10];
  const float* w2a=(const float*)d_in[11], *b2a=(const float*)d_in[12];
  const float* w2b=(const float*)d_in[13], *b2b=(const float*)d_in[14];
  const float* w3a=(const float*)d_in[15], *b3a=(const float*)d_in[16];
  const float* w3b=(const float*)d_in[17], *b3b=(const float*)d_in[18];
  const float* fc1w=(const float*)d_in[19],*fc1b=(const float*)d_in[20];
  const float* fc2w=(const float*)d_in[21],*fc2b=(const float*)d_in[22];
  float* out = (float*)d_out;

  // workspace layout (unchanged size: 155.7 MB)
  char* base = (char*)d_ws;
  float* P      = (float*)base;  base += (size_t)N_TOTAL*8*4;        // 32.77 MB
  float* Q      = (float*)base;  base += (size_t)N_TOTAL*8*4;        // 32.77 MB
  size_t atomic_need = (size_t)(base - (char*)d_ws);
  int2*  row2   = (int2*)base;   base += (size_t)N_TOTAL*8;          // 8.19 MB
  int*   cnt    = (int*)base;    base += 4096*4;                     // 16 KB (fine counters)
  int*   packed = (int*)base;    base += (size_t)NBUCK*BCAP*4;       // 81.92 MB
  size_t need = (size_t)(base - (char*)d_ws);

  // coarse staging aliases [P|Q|row2] (73.7 MB); written only BEFORE P/Q/row2 are live
  int* coarse = (int*)P;                               // NCOARSE*CCAP ints = 73.47 MB
  int* cntC   = coarse + (size_t)NCOARSE*CCAP;         // 250 ints, still inside alias area

  const int nb_nodes = (N_TOTAL + 255)/256;     // 4000
  const int nb_nf    = (N_TOTAL*8 + 255)/256;   // 32000

  if (ws_size >= need){
    // ---- two-level LDS-staged partition + CSR build (reused by all 4 layers) ----
    hipMemsetAsync(cnt, 0, (size_t)NBUCK*4, stream);
    hipMemsetAsync(cntC, 0, (size_t)NCOARSE*4, stream);
    k_part1<<<N_EDGES/CTILE,256,0,stream>>>(src, dst, cntC, coarse);
    dim3 g2(NCOARSE, (CCAP + CTILE - 1)/CTILE);        // 250 x 18
    k_part2<<<g2,256,0,stream>>>(coarse, cntC, cnt, packed);
    k_csr<<<NBUCK,256,0,stream>>>(packed, cnt, row2);

    // ---- fused conv layers, ping-pong P <-> Q ----
    k_init<<<nb_nodes,256,0,stream>>>(x, w0a, P);
    k_aggf<1><<<nb_nf,256,0,stream>>>(P, row2, packed, b0a, w0b, b0b, w1a, Q);
    k_aggf<1><<<nb_nf,256,0,stream>>>(Q, row2, packed, b1a, w1b, b1b, w2a, P);
    k_aggf<1><<<nb_nf,256,0,stream>>>(P, row2, packed, b2a, w2b, b2b, w3a, Q);
    k_aggf<0><<<nb_nf,256,0,stream>>>(Q, row2, packed, b3a, nullptr, nullptr, nullptr, P);
    k_readout<<<512,256,0,stream>>>(P, w3b, b3b, fc1w, fc1b, fc2w, fc2b, out);
  } else if (ws_size >= atomic_need){
    // ---- atomic fallback ----
    k_init<<<nb_nodes,256,0,stream>>>(x, w0a, P);
    k_qinit<<<nb_nf,256,0,stream>>>(P, b0a, Q);
    k_scatter<<<(N_EDGES*8)/256,256,0,stream>>>(src,dst,P,Q);
    k_mid <<<nb_nodes,256,0,stream>>>(P, Q, w0b, b0b, w1a);
    k_qinit<<<nb_nf,256,0,stream>>>(P, b1a, Q);
    k_scatter<<<(N_EDGES*8)/256,256,0,stream>>>(src,dst,P,Q);
    k_mid <<<nb_nodes,256,0,stream>>>(P, Q, w1b, b1b, w2a);
    k_qinit<<<nb_nf,256,0,stream>>>(P, b2a, Q);
    k_scatter<<<(N_EDGES*8)/256,256,0,stream>>>(src,dst,P,Q);
    k_mid <<<nb_nodes,256,0,stream>>>(P, Q, w2b, b2b, w3a);
    k_qinit<<<nb_nf,256,0,stream>>>(P, b3a, Q);
    k_scatter<<<(N_EDGES*8)/256,256,0,stream>>>(src,dst,P,Q);
    k_readout<<<512,256,0,stream>>>(Q, w3b, b3b, fc1w, fc1b, fc2w, fc2b, out);
  }
}